// Round 3
// baseline (1940.125 us; speedup 1.0000x reference)
//
#include <hip/hip_runtime.h>

typedef unsigned short u16;
typedef __bf16 bf16x8 __attribute__((ext_vector_type(8)));
typedef float f32x4 __attribute__((ext_vector_type(4)));

#define D 64
#define LPITCH 136   // 128 + 8 bf16 pad (sA row pitch)
#define CHUNKS 512   // edge-array partitions (2 blocks/CU)
#define BSHIFT 6     // 64-node buckets == layer tiles; nbuck = 1563 for N=100000
#define MAXB 1600    // LDS array cap for buckets (N <= 102400)
#define CCAP 1280    // LDS edge-list capacity per 64-node tile (mean ~1024, +8 sigma)
#define TGRID 1024   // tails kernel grid (4 blocks/CU)

__device__ __forceinline__ float b2f(u16 u) {
    unsigned v = ((unsigned)u) << 16;
    float f;
    __builtin_memcpy(&f, &v, 4);
    return f;
}
__device__ __forceinline__ float u2f_lo(unsigned u) {
    unsigned v = u << 16;
    float f;
    __builtin_memcpy(&f, &v, 4);
    return f;
}
__device__ __forceinline__ float u2f_hi(unsigned u) {
    unsigned v = u & 0xFFFF0000u;
    float f;
    __builtin_memcpy(&f, &v, 4);
    return f;
}
__device__ __forceinline__ u16 f2b(float f) {
    unsigned u;
    __builtin_memcpy(&u, &f, 4);
    u = u + 0x7FFFu + ((u >> 16) & 1u);   // RNE
    return (u16)(u >> 16);
}
__device__ __forceinline__ bf16x8 ld_frag(const u16* p) {
    union { uint4 u; bf16x8 b; } cv;
    cv.u = *(const uint4*)p;
    return cv.b;
}

// ---------------- binA: per-chunk tile-bucket histogram ----------------------------
__global__ __launch_bounds__(256) void binA_kernel(const int* __restrict__ dst, int E,
                                                   int* __restrict__ H, int nbuck,
                                                   int eper) {
    __shared__ int hist[MAXB];
    int t = threadIdx.x;
    int c = blockIdx.x;
    for (int i = t; i < MAXB; i += 256) hist[i] = 0;
    __syncthreads();
    int beg = c * eper, end = min(beg + eper, E);
    for (int i = beg + t; i < end; i += 256)
        atomicAdd(&hist[dst[i] >> BSHIFT], 1);
    __syncthreads();
    for (int b = t; b < nbuck; b += 256) H[c * nbuck + b] = hist[b];
}

// ---------------- tails: f32->bf16 cvt + weight transposes (1024 blocks) ------------
__global__ __launch_bounds__(256) void tail_kernel(const float* __restrict__ xf,
                                                   u16* __restrict__ xb, int total4,
                                                   const float* __restrict__ wl,
                                                   const float* __restrict__ wr,
                                                   const float* __restrict__ wres,
                                                   const float* __restrict__ wfc,
                                                   u16* __restrict__ WtL,
                                                   u16* __restrict__ WresT,
                                                   u16* __restrict__ WfcT) {
    int gid = blockIdx.x * 256 + threadIdx.x;
    int gstr = TGRID * 256;
    for (int i = gid; i < total4; i += gstr) {
        float4 v = *(const float4*)(xf + i * 4);
        ushort4 o;
        o.x = f2b(v.x); o.y = f2b(v.y); o.z = f2b(v.z); o.w = f2b(v.w);
        *(ushort4*)(xb + i * 4) = o;
    }
    // W^T prep: [L][64 rows][128 cols] = concat(w_l^T, w_r^T)
    for (int idx = gid; idx < 3 * 64 * 128; idx += gstr) {
        int l = idx >> 13;
        int rem = idx & 8191;
        int n = rem >> 7;
        int k = rem & 127;
        float v = (k < 64) ? wl[l * 4096 + k * 64 + n] : wr[l * 4096 + (k - 64) * 64 + n];
        WtL[idx] = f2b(v);
    }
    for (int idx = gid; idx < 4096; idx += gstr) {
        int n = idx >> 6, k = idx & 63;
        WresT[idx] = f2b(wres[k * 64 + n]);
        WfcT[idx] = f2b(wfc[k * 64 + n]);
    }
}

// ---------------- binS2: per-bucket scan over chunk counts -> Orel + T[b] -----------
// CHUNKS=512 values scanned by 256 threads (2 per thread). grid = nbuck blocks.
__global__ __launch_bounds__(256) void binS2_kernel(const int* __restrict__ H,
                                                    int* __restrict__ Orel,
                                                    int* __restrict__ T,
                                                    int nbuck) {
    __shared__ int ss[256];
    int b = blockIdx.x;
    int t = threadIdx.x;
    int h0 = H[(2 * t) * nbuck + b];
    int h1 = H[(2 * t + 1) * nbuck + b];
    int s = h0 + h1;
    ss[t] = s;
    __syncthreads();
    for (int off = 1; off < 256; off <<= 1) {
        int v = (t >= off) ? ss[t - off] : 0;
        __syncthreads();
        ss[t] += v;
        __syncthreads();
    }
    int excl = ss[t] - s;
    Orel[(2 * t) * nbuck + b] = excl;
    Orel[(2 * t + 1) * nbuck + b] = excl + h0;
    if (t == 255) T[b] = ss[255];
}

// ---------------- tscan: exclusive scan of T (nbuck <= 1792) -> tile_ptr ------------
__global__ __launch_bounds__(256) void tscan_kernel(const int* __restrict__ T,
                                                    int* __restrict__ tile_ptr,
                                                    int nbuck, int E) {
    __shared__ int ss[256];
    int t = threadIdx.x;
    int vals[7];
    int loc = 0;
#pragma unroll
    for (int k = 0; k < 7; k++) {
        int i = t * 7 + k;
        int v = (i < nbuck) ? T[i] : 0;
        vals[k] = loc;
        loc += v;
    }
    ss[t] = loc;
    __syncthreads();
    for (int off = 1; off < 256; off <<= 1) {
        int u = (t >= off) ? ss[t - off] : 0;
        __syncthreads();
        ss[t] += u;
        __syncthreads();
    }
    int base = ss[t] - loc;
#pragma unroll
    for (int k = 0; k < 7; k++) {
        int i = t * 7 + k;
        if (i < nbuck) tile_ptr[i] = base + vals[k];
    }
    if (t == 0) tile_ptr[nbuck] = E;
}

// ---------------- binB: scatter packed (src | dlow<<17) into tile buckets ----------
__global__ __launch_bounds__(256) void binB_kernel(const int* __restrict__ src,
                                                   const int* __restrict__ dst, int E,
                                                   const int* __restrict__ tile_ptr,
                                                   const int* __restrict__ Orel,
                                                   int* __restrict__ staging,
                                                   int nbuck, int eper) {
    __shared__ int sc[MAXB];
    int t = threadIdx.x;
    int c = blockIdx.x;
    for (int b = t; b < nbuck; b += 256)
        sc[b] = tile_ptr[b] + Orel[c * nbuck + b];
    __syncthreads();
    int beg = c * eper, end = min(beg + eper, E);
    for (int i = beg + t; i < end; i += 256) {
        int d = dst[i];
        int b = d >> BSHIFT;
        int p = atomicAdd(&sc[b], 1);
        staging[p] = src[i] | ((d & 63) << 17);
    }
}

// ---------------- fused SAGE layer ---------------------------------------------------
// Tile-bucketed unsorted edges; gather-mean via LDS f32 atomics into aggF (overlaid
// on sA), then convert to bf16 rows, GEMM (B-frags direct from L1-resident global W),
// LN + ReLU + residual. LDS ~23KB -> ~2x occupancy vs sB-staged variant.
__global__ __launch_bounds__(256, 6) void layer_kernel(const u16* __restrict__ xb_in,
                                                       const int* __restrict__ tile_ptr,
                                                       const int* __restrict__ staging,
                                                       const u16* __restrict__ Wt,    // [64][128]
                                                       const float* __restrict__ bl,
                                                       const float* __restrict__ gam,
                                                       const float* __restrict__ bet,
                                                       const u16* __restrict__ WresT, // [64][64]
                                                       const float* __restrict__ bres,
                                                       const u16* __restrict__ WfcT,  // [64][64]
                                                       const float* __restrict__ bfc,
                                                       u16* __restrict__ xb_out,
                                                       float* __restrict__ fout,
                                                       int N, int layer0, int final_) {
    __shared__ __align__(16) u16 sA[64 * LPITCH];   // phase1: aggF f32[64*65]; phase2: bf16 [64][136]
    __shared__ int lcol[CCAP];
    __shared__ int dcnt[64];
    int tid = threadIdx.x;
    int base = blockIdx.x * 64;
    int lane = tid & 63;
    int w = tid >> 6;
    float* aggF = (float*)sA;          // 64 rows * 65 floats = 16640 B <= 17408 B

    int e0 = tile_ptr[blockIdx.x];
    int e1 = tile_ptr[blockIdx.x + 1];
    int tileE = e1 - e0;

    // preload this block's x rows (written to sA after gather) — T14 issue-early
    uint4 xr[2];
#pragma unroll
    for (int i = 0; i < 2; i++) {
        int idx = i * 256 + tid;
        int r = idx >> 3, c = idx & 7;
        int node = base + r;
        xr[i] = make_uint4(0, 0, 0, 0);
        if (node < N) xr[i] = *(const uint4*)(xb_in + node * D + c * 8);
    }

    // zero accumulator + degree counters
    for (int i = tid; i < 64 * 65; i += 256) aggF[i] = 0.f;
    if (tid < 64) dcnt[tid] = 0;
    __syncthreads();

    bool fits = tileE <= CCAP;
    if (fits) {
        for (int i = tid; i < tileE; i += 256) {
            int word = staging[e0 + i];
            lcol[i] = word;
            atomicAdd(&dcnt[word >> 17], 1);
        }
    } else {
        for (int i = tid; i < tileE; i += 256)
            atomicAdd(&dcnt[staging[e0 + i] >> 17], 1);
    }
    __syncthreads();

    // gather: 8 lanes per edge (chunk = tid&7), LDS f32 atomic accumulate.
    // aggF pitch 65 -> bank = (dl + 8*chunk + j) & 31 -> ~2-way (free, m136)
    int chunk = tid & 7;
    auto run_gather = [&](auto LD) {
        for (int i = (tid >> 3); i < tileE; i += 32) {
            int word = LD(i);
            int s = word & 0x1FFFF;
            int dl = word >> 17;
            uint4 v = *(const uint4*)(xb_in + s * D + chunk * 8);
            float* ap = &aggF[dl * 65 + chunk * 8];
            atomicAdd(ap + 0, u2f_lo(v.x));
            atomicAdd(ap + 1, u2f_hi(v.x));
            atomicAdd(ap + 2, u2f_lo(v.y));
            atomicAdd(ap + 3, u2f_hi(v.y));
            atomicAdd(ap + 4, u2f_lo(v.z));
            atomicAdd(ap + 5, u2f_hi(v.z));
            atomicAdd(ap + 6, u2f_lo(v.w));
            atomicAdd(ap + 7, u2f_hi(v.w));
        }
    };
    if (fits) run_gather([&](int i) { return lcol[i]; });
    else      run_gather([&](int i) { return staging[e0 + i]; });
    __syncthreads();

    // convert aggF (f32, pitch 65) -> sA rows (bf16, pitch 136), apply 1/deg.
    // read-all-to-regs then barrier then write (regions overlap across rows).
    {
        int n = tid >> 2;
        int qq = tid & 3;
        int dg = dcnt[n];
        float m = dg > 0 ? 1.f / (float)dg : 0.f;
        float tmp[16];
#pragma unroll
        for (int j = 0; j < 16; j++) tmp[j] = aggF[n * 65 + qq * 16 + j] * m;
        __syncthreads();
        uint4 o0, o1;
        o0.x = (unsigned)f2b(tmp[0]) | ((unsigned)f2b(tmp[1]) << 16);
        o0.y = (unsigned)f2b(tmp[2]) | ((unsigned)f2b(tmp[3]) << 16);
        o0.z = (unsigned)f2b(tmp[4]) | ((unsigned)f2b(tmp[5]) << 16);
        o0.w = (unsigned)f2b(tmp[6]) | ((unsigned)f2b(tmp[7]) << 16);
        o1.x = (unsigned)f2b(tmp[8]) | ((unsigned)f2b(tmp[9]) << 16);
        o1.y = (unsigned)f2b(tmp[10]) | ((unsigned)f2b(tmp[11]) << 16);
        o1.z = (unsigned)f2b(tmp[12]) | ((unsigned)f2b(tmp[13]) << 16);
        o1.w = (unsigned)f2b(tmp[14]) | ((unsigned)f2b(tmp[15]) << 16);
        *(uint4*)&sA[n * LPITCH + qq * 16] = o0;
        *(uint4*)&sA[n * LPITCH + qq * 16 + 8] = o1;
        // stage preloaded x rows into cols 64..127 (same phase: all aggF reads done)
#pragma unroll
        for (int i = 0; i < 2; i++) {
            int idx = i * 256 + tid;
            int r = idx >> 3, c = idx & 7;
            *(uint4*)&sA[r * LPITCH + 64 + c * 8] = xr[i];
        }
    }
    __syncthreads();

    // GEMM stage: A from sA, B direct from global (Wt is 16KB, L1/L2-resident)
    int q = lane >> 4;
    int ln = lane & 15;
    f32x4 acc[4] = {{0, 0, 0, 0}, {0, 0, 0, 0}, {0, 0, 0, 0}, {0, 0, 0, 0}};
    f32x4 accr[4] = {{0, 0, 0, 0}, {0, 0, 0, 0}, {0, 0, 0, 0}, {0, 0, 0, 0}};
    const u16* aRow = &sA[(w * 16 + ln) * LPITCH];

#pragma unroll
    for (int c = 0; c < 4; c++) {       // K = 128
        bf16x8 a = ld_frag(&aRow[c * 32 + q * 8]);
#pragma unroll
        for (int t = 0; t < 4; t++) {
            bf16x8 b = ld_frag(Wt + (t * 16 + ln) * 128 + c * 32 + q * 8);
            acc[t] = __builtin_amdgcn_mfma_f32_16x16x32_bf16(a, b, acc[t], 0, 0, 0);
        }
    }
    if (layer0) {                       // residual = x @ w_res
#pragma unroll
        for (int c = 0; c < 2; c++) {
            bf16x8 a = ld_frag(&aRow[64 + c * 32 + q * 8]);
#pragma unroll
            for (int t = 0; t < 4; t++) {
                bf16x8 b = ld_frag(WresT + (t * 16 + ln) * 64 + c * 32 + q * 8);
                accr[t] = __builtin_amdgcn_mfma_f32_16x16x32_bf16(a, b, accr[t], 0, 0, 0);
            }
        }
    }

    float bcol[4], gcol[4], btcol[4], brcol[4];
#pragma unroll
    for (int t = 0; t < 4; t++) {
        int colI = t * 16 + ln;
        bcol[t] = bl[colI];
        gcol[t] = gam[colI];
        btcol[t] = bet[colI];
        brcol[t] = layer0 ? bres[colI] : 0.f;
    }
#pragma unroll
    for (int t = 0; t < 4; t++)
#pragma unroll
        for (int r = 0; r < 4; r++) acc[t][r] += bcol[t];

    float ps[4], pq[4];
#pragma unroll
    for (int r = 0; r < 4; r++) {
        float s = 0, s2 = 0;
#pragma unroll
        for (int t = 0; t < 4; t++) { float h = acc[t][r]; s += h; s2 += h * h; }
        ps[r] = s; pq[r] = s2;
    }
    for (int off = 1; off < 16; off <<= 1) {
#pragma unroll
        for (int r = 0; r < 4; r++) {
            ps[r] += __shfl_xor(ps[r], off, 64);
            pq[r] += __shfl_xor(pq[r], off, 64);
        }
    }
    // epilogue -> sA cols 0..63 (wave-local rows; in-wave LDS dep, no barrier)
#pragma unroll
    for (int r = 0; r < 4; r++) {
        int nb = w * 16 + q * 4 + r;
        float mu = ps[r] * (1.f / 64.f);
        float var = pq[r] * (1.f / 64.f) - mu * mu;
        var = var < 0.f ? 0.f : var;
        float rstd = rsqrtf(var + 1e-5f);
#pragma unroll
        for (int t = 0; t < 4; t++) {
            int colI = t * 16 + ln;
            float hn = (acc[t][r] - mu) * rstd * gcol[t] + btcol[t];
            hn = hn > 0.f ? hn : 0.f;
            float res = layer0 ? (accr[t][r] + brcol[t])
                               : b2f(sA[nb * LPITCH + 64 + colI]);
            sA[nb * LPITCH + colI] = f2b(hn + res);
        }
    }

    if (final_) {
        // FC: out = x3 @ w_fc + b_fc; direct global stores (4x64B segs per instr)
        f32x4 accf[4] = {{0, 0, 0, 0}, {0, 0, 0, 0}, {0, 0, 0, 0}, {0, 0, 0, 0}};
#pragma unroll
        for (int c = 0; c < 2; c++) {
            bf16x8 a = ld_frag(&aRow[c * 32 + q * 8]);
#pragma unroll
            for (int t = 0; t < 4; t++) {
                bf16x8 b = ld_frag(WfcT + (t * 16 + ln) * 64 + c * 32 + q * 8);
                accf[t] = __builtin_amdgcn_mfma_f32_16x16x32_bf16(a, b, accf[t], 0, 0, 0);
            }
        }
#pragma unroll
        for (int r = 0; r < 4; r++) {
            int nb = w * 16 + q * 4 + r;
            int node = base + nb;
            if (node < N) {
#pragma unroll
                for (int t = 0; t < 4; t++) {
                    int colI = t * 16 + ln;
                    fout[node * D + colI] = accf[t][r] + bfc[colI];
                }
            }
        }
    } else {
        // coalesced writeback of this wave's 16 rows (2 uint4 per thread)
#pragma unroll
        for (int i = 0; i < 2; i++) {
            int idx = i * 64 + lane;
            int row = w * 16 + (idx >> 3);
            int ch = idx & 7;
            int node = base + row;
            if (node < N)
                *(uint4*)(xb_out + node * D + ch * 8) = *(const uint4*)&sA[row * LPITCH + ch * 8];
        }
    }
}

extern "C" void kernel_launch(void* const* d_in, const int* in_sizes, int n_in,
                              void* d_out, int out_size, void* d_ws, size_t ws_size,
                              hipStream_t stream) {
    const float* x_in = (const float*)d_in[0];
    const int* e_src = (const int*)d_in[1];
    const int* e_dst = (const int*)d_in[2];
    const float* w_l = (const float*)d_in[3];
    const float* b_l = (const float*)d_in[4];
    const float* w_r = (const float*)d_in[5];
    const float* gam = (const float*)d_in[6];
    const float* bet = (const float*)d_in[7];
    const float* w_res = (const float*)d_in[8];
    const float* b_res = (const float*)d_in[9];
    const float* w_fc = (const float*)d_in[10];
    const float* b_fc = (const float*)d_in[11];
    float* out = (float*)d_out;

    const int N = in_sizes[0] / D;
    const int E = in_sizes[1];
    const int nbuck = ((N - 1) >> BSHIFT) + 1;   // 1563 for N=100000 (<= MAXB)
    const int eper = (E + CHUNKS - 1) / CHUNKS;

    size_t o = 0;
    auto carve = [&](size_t bytes) {
        size_t cur = o;
        o += (bytes + 255) & ~(size_t)255;
        return (char*)d_ws + cur;
    };
    int* staging = (int*)carve((size_t)E * 4);
    int* Hh = (int*)carve((size_t)CHUNKS * nbuck * 4);
    int* Orel = (int*)carve((size_t)CHUNKS * nbuck * 4);
    int* Tb = (int*)carve((size_t)nbuck * 4);
    int* tile_ptr = (int*)carve((size_t)(nbuck + 1) * 4);
    u16* WtL = (u16*)carve(3 * 64 * 128 * 2);
    u16* WresT = (u16*)carve(64 * 64 * 2);
    u16* WfcT = (u16*)carve(64 * 64 * 2);
    u16* xbA = (u16*)carve((size_t)N * D * 2);
    u16* xbB = (u16*)carve((size_t)N * D * 2);

    // tile-granular edge bucketing (no per-node CSR, no row_ptr/inv_deg)
    binA_kernel<<<CHUNKS, 256, 0, stream>>>(e_dst, E, Hh, nbuck, eper);
    tail_kernel<<<TGRID, 256, 0, stream>>>(x_in, xbA, N * D / 4,
                                           w_l, w_r, w_res, w_fc, WtL, WresT, WfcT);
    binS2_kernel<<<nbuck, 256, 0, stream>>>(Hh, Orel, Tb, nbuck);
    tscan_kernel<<<1, 256, 0, stream>>>(Tb, tile_ptr, nbuck, E);
    binB_kernel<<<CHUNKS, 256, 0, stream>>>(e_src, e_dst, E, tile_ptr, Orel, staging,
                                            nbuck, eper);

    int gridT = (N + 63) / 64;

    // layer 0: xbA -> xbB  (residual via w_res MFMA)
    layer_kernel<<<gridT, 256, 0, stream>>>(xbA, tile_ptr, staging, WtL,
                                            b_l, gam, bet, WresT, b_res,
                                            WfcT, b_fc, xbB, out, N, 1, 0);
    // layer 1: xbB -> xbA
    layer_kernel<<<gridT, 256, 0, stream>>>(xbB, tile_ptr, staging, WtL + 8192,
                                            b_l + 64, gam + 64, bet + 64, WresT, b_res,
                                            WfcT, b_fc, xbA, out, N, 0, 0);
    // layer 2 + fused fc: xbA -> out (f32)
    layer_kernel<<<gridT, 256, 0, stream>>>(xbA, tile_ptr, staging, WtL + 16384,
                                            b_l + 128, gam + 128, bet + 128, WresT, b_res,
                                            WfcT, b_fc, xbB, out, N, 0, 1);
}

// Round 4
// 416.570 us; speedup vs baseline: 4.6574x; 4.6574x over previous
//
#include <hip/hip_runtime.h>

typedef unsigned short u16;
typedef __bf16 bf16x8 __attribute__((ext_vector_type(8)));
typedef float f32x4 __attribute__((ext_vector_type(4)));

#define D 64
#define LPITCH 136   // 128 + 8 bf16 pad
#define CHUNKS 256   // edge-array partitions == fused-kernel grid
#define BSHIFT 9     // 512 nodes per bucket (nbuck = 196 for N = 100000; max 512)
#define CCAP 1280    // LDS edge-list capacity per 64-node tile (mean ~1024, +2 sigma)

__device__ __forceinline__ float b2f(u16 u) {
    unsigned v = ((unsigned)u) << 16;
    float f;
    __builtin_memcpy(&f, &v, 4);
    return f;
}
__device__ __forceinline__ float u2f_lo(unsigned u) {
    unsigned v = u << 16;
    float f;
    __builtin_memcpy(&f, &v, 4);
    return f;
}
__device__ __forceinline__ float u2f_hi(unsigned u) {
    unsigned v = u & 0xFFFF0000u;
    float f;
    __builtin_memcpy(&f, &v, 4);
    return f;
}
__device__ __forceinline__ u16 f2b(float f) {
    unsigned u;
    __builtin_memcpy(&u, &f, 4);
    u = u + 0x7FFFu + ((u >> 16) & 1u);   // RNE
    return (u16)(u >> 16);
}
__device__ __forceinline__ bf16x8 ld_frag(const u16* p) {
    union { uint4 u; bf16x8 b; } cv;
    cv.u = *(const uint4*)p;
    return cv.b;
}

// Device-scope barrier for a co-resident grid (grid == 256 blocks <= 256 CUs).
// bar[0] = arrive counter (must be 0 at kernel entry; self-resetting),
// bar[1] = generation (monotonic; any start value works).
__device__ __forceinline__ void gbar(int* bar, int nb) {
    __threadfence();                       // release: make this block's writes visible
    __syncthreads();
    if (threadIdx.x == 0) {
        int g = __hip_atomic_load(bar + 1, __ATOMIC_RELAXED, __HIP_MEMORY_SCOPE_AGENT);
        int old = __hip_atomic_fetch_add(bar, 1, __ATOMIC_RELAXED, __HIP_MEMORY_SCOPE_AGENT);
        if (old == nb - 1) {
            __hip_atomic_store(bar, 0, __ATOMIC_RELAXED, __HIP_MEMORY_SCOPE_AGENT);
            __hip_atomic_fetch_add(bar + 1, 1, __ATOMIC_RELEASE, __HIP_MEMORY_SCOPE_AGENT);
        } else {
            while (__hip_atomic_load(bar + 1, __ATOMIC_RELAXED, __HIP_MEMORY_SCOPE_AGENT) == g)
                __builtin_amdgcn_s_sleep(8);
        }
        __threadfence();                   // acquire: invalidate stale L1/L2 before reads
    }
    __syncthreads();
}

// ---------------- fused CSR build: hist -> scan -> scatter -> per-node sort ---------
// Plus x f32->bf16 conversion and weight transposes folded into phase 0.
// One kernel, 3 device barriers, replaces the former 5-kernel chain.
__global__ __launch_bounds__(256) void csr_fused(
    const int* __restrict__ src, const int* __restrict__ dst, int E,
    const float* __restrict__ xf, u16* __restrict__ xb, int total4,
    const float* __restrict__ wl, const float* __restrict__ wr,
    const float* __restrict__ wres, const float* __restrict__ wfc,
    u16* __restrict__ WtL, u16* __restrict__ WresT, u16* __restrict__ WfcT,
    int* __restrict__ H, int* __restrict__ Orel, int* __restrict__ T,
    int* __restrict__ staging, int* __restrict__ row_ptr,
    float* __restrict__ inv_deg, int* __restrict__ col,
    int* __restrict__ bar, int N, int nbuck, int eper) {

    __shared__ int shA[512];
    __shared__ int shB[512];
    __shared__ int sm[256];
    __shared__ int tb[513];

    int t = threadIdx.x;
    int c = blockIdx.x;
    int gid = c * 256 + t;
    int nb = gridDim.x;
    int beg = c * eper, end = min(beg + eper, E);

    // ---- P0: per-chunk bucket histogram + cvt/weight tails ----
    shA[t] = 0;
    shA[t + 256] = 0;
    __syncthreads();
    for (int i = beg + t; i < end; i += 256)
        atomicAdd(&shA[dst[i] >> BSHIFT], 1);
    if (gid == 0) row_ptr[N] = E;
    for (int i = gid; i < total4; i += CHUNKS * 256) {
        float4 v = *(const float4*)(xf + i * 4);
        ushort4 o;
        o.x = f2b(v.x); o.y = f2b(v.y); o.z = f2b(v.z); o.w = f2b(v.w);
        *(ushort4*)(xb + i * 4) = o;
    }
    for (int idx = gid; idx < 3 * 64 * 128; idx += CHUNKS * 256) {
        int l = idx >> 13;
        int rem = idx & 8191;
        int n = rem >> 7;
        int k = rem & 127;
        float v = (k < 64) ? wl[l * 4096 + k * 64 + n] : wr[l * 4096 + (k - 64) * 64 + n];
        WtL[idx] = f2b(v);
    }
    for (int idx = gid; idx < 4096; idx += CHUNKS * 256) {
        int n = idx >> 6, k = idx & 63;
        WresT[idx] = f2b(wres[k * 64 + n]);
        WfcT[idx] = f2b(wfc[k * 64 + n]);
    }
    __syncthreads();
    for (int b = t; b < nbuck; b += 256) H[c * nbuck + b] = shA[b];

    gbar(bar, nb);

    // ---- P1: per-bucket exclusive scan over chunk counts -> Orel, T ----
    for (int b = c; b < nbuck; b += nb) {
        int h = H[t * nbuck + b];
        sm[t] = h;
        __syncthreads();
        for (int off = 1; off < 256; off <<= 1) {
            int v = (t >= off) ? sm[t - off] : 0;
            __syncthreads();
            sm[t] += v;
            __syncthreads();
        }
        Orel[t * nbuck + b] = sm[t] - h;
        if (t == 255) T[b] = sm[255];
        __syncthreads();
    }

    gbar(bar, nb);

    // ---- P2: scatter packed (src | dlow<<17) into bucket cells; build tb ----
    {
        int v0 = (2 * t < nbuck) ? T[2 * t] : 0;
        int v1 = (2 * t + 1 < nbuck) ? T[2 * t + 1] : 0;
        int s = v0 + v1;
        sm[t] = s;
        __syncthreads();
        for (int off = 1; off < 256; off <<= 1) {
            int u = (t >= off) ? sm[t - off] : 0;
            __syncthreads();
            sm[t] += u;
            __syncthreads();
        }
        int base0 = sm[t] - s;
        int o0 = (2 * t < nbuck) ? Orel[c * nbuck + 2 * t] : 0;
        int o1 = (2 * t + 1 < nbuck) ? Orel[c * nbuck + 2 * t + 1] : 0;
        shA[2 * t] = base0 + o0;
        shA[2 * t + 1] = base0 + v0 + o1;
        tb[2 * t] = base0;                 // bucket bases persist in LDS for P3
        tb[2 * t + 1] = base0 + v0;
        if (t == 255) tb[512] = sm[255];
        __syncthreads();
        const int mask = (1 << BSHIFT) - 1;
        for (int i = beg + t; i < end; i += 256) {
            int d = dst[i];
            int b = d >> BSHIFT;
            int p = atomicAdd(&shA[b], 1);
            staging[p] = src[i] | ((d & mask) << 17);
        }
    }

    gbar(bar, nb);

    // ---- P3: per-bucket degree hist + scan + col scatter (LDS only) ----
    for (int b = c; b < nbuck; b += nb) {
        int sbeg = tb[b], send = tb[b + 1];
        shA[t] = 0;
        shA[t + 256] = 0;
        __syncthreads();
        int node0 = b << BSHIFT;
        int nn = min(1 << BSHIFT, N - node0);
        for (int i = sbeg + t; i < send; i += 256)
            atomicAdd(&shA[staging[i] >> 17], 1);
        __syncthreads();
        int c0 = shA[2 * t], c1 = shA[2 * t + 1];
        sm[t] = c0 + c1;
        __syncthreads();
        for (int off = 1; off < 256; off <<= 1) {
            int u = (t >= off) ? sm[t - off] : 0;
            __syncthreads();
            sm[t] += u;
            __syncthreads();
        }
        int excl = sm[t] - c0 - c1;
        shB[2 * t] = excl;
        shB[2 * t + 1] = excl + c0;
        __syncthreads();
        for (int i = t; i < nn; i += 256) {
            row_ptr[node0 + i] = sbeg + shB[i];
            int dd = shA[i];
            inv_deg[node0 + i] = dd > 0 ? 1.0f / (float)dd : 0.0f;
        }
        __syncthreads();
        for (int i = sbeg + t; i < send; i += 256) {
            int word = staging[i];
            int ld = word >> 17;
            int k = atomicSub(&shA[ld], 1) - 1;
            col[sbeg + shB[ld] + k] = word & 0x1FFFF;
        }
        __syncthreads();
    }
}

// ---------------- fused SAGE layer: gather-mean + GEMM + LN + ReLU + residual --------
// R9 static-slot gather (best measured) + tile edge-list staged to LDS (lcol).
// NOTE (R3 lesson): LDS f32-atomic aggregation is ~13x slower (ds_add ~1/cyc/CU);
// register slot-accumulation + per-node-sorted col is the fast structure.
__global__ __launch_bounds__(256, 4) void layer_kernel(const u16* __restrict__ xb_in,
                                                       const int* __restrict__ row_ptr,
                                                       const int* __restrict__ col,
                                                       const float* __restrict__ inv_deg,
                                                       const u16* __restrict__ Wt,    // [64][128]
                                                       const float* __restrict__ bl,
                                                       const float* __restrict__ gam,
                                                       const float* __restrict__ bet,
                                                       const u16* __restrict__ WresT, // [64][64]
                                                       const float* __restrict__ bres,
                                                       const u16* __restrict__ WfcT,  // [64][64]
                                                       const float* __restrict__ bfc,
                                                       u16* __restrict__ xb_out,
                                                       float* __restrict__ fout,
                                                       int N, int layer0, int final_) {
    __shared__ __align__(16) u16 sA[64 * LPITCH];
    __shared__ __align__(16) u16 sB[64 * LPITCH];   // weights; reused as f32 stage in final
    __shared__ int lcol[CCAP];
    __shared__ int rp[65];
    __shared__ float ideg[64];
    int tid = threadIdx.x;
    int base = blockIdx.x * 64;
    int lane = tid & 63;
    int w = tid >> 6;

    // stage B (W^T rows), 4 uint4 per thread
#pragma unroll
    for (int i = 0; i < 4; i++) {
        int idx = i * 256 + tid;
        int r = idx >> 4, c = idx & 15;
        *(uint4*)&sB[r * LPITCH + c * 8] = *(const uint4*)(Wt + idx * 8);
    }
    // stage x rows into sA cols 64..127, 2 uint4 per thread
#pragma unroll
    for (int i = 0; i < 2; i++) {
        int idx = i * 256 + tid;
        int r = idx >> 3, c = idx & 7;
        int node = base + r;
        uint4 v = make_uint4(0, 0, 0, 0);
        if (node < N) v = *(const uint4*)(xb_in + node * D + c * 8);
        *(uint4*)&sA[r * LPITCH + 64 + c * 8] = v;
    }
    if (tid < 65) rp[tid] = row_ptr[min(base + tid, N)];
    if (tid < 64) ideg[tid] = (base + tid < N) ? inv_deg[base + tid] : 0.f;
    __syncthreads();

    int e0 = rp[0];
    int tileE = rp[64] - e0;
    bool fits = tileE <= CCAP;
    if (fits) {
        for (int i = tid; i < tileE; i += 256) lcol[i] = col[e0 + i];
    }
    __syncthreads();

    // gather stage: slot-per-node, 2 rounds x 8 slots per wave = 16 nodes/wave
    int slot = lane >> 3;
    int chunk = lane & 7;
    auto run_gather = [&](auto LD) {
#pragma unroll
        for (int r = 0; r < 2; r++) {
            int node_l = w * 16 + r * 8 + slot;
            float a0 = 0, a1 = 0, a2 = 0, a3 = 0, a4 = 0, a5 = 0, a6 = 0, a7 = 0;
            int e = rp[node_l], end = rp[node_l + 1];
#define ACC(v)                                          \
    a0 += u2f_lo(v.x); a1 += u2f_hi(v.x);               \
    a2 += u2f_lo(v.y); a3 += u2f_hi(v.y);               \
    a4 += u2f_lo(v.z); a5 += u2f_hi(v.z);               \
    a6 += u2f_lo(v.w); a7 += u2f_hi(v.w);
            for (; e + 7 < end; e += 8) {
                int s0 = LD(e),     s1 = LD(e + 1), s2 = LD(e + 2), s3 = LD(e + 3);
                int s4 = LD(e + 4), s5 = LD(e + 5), s6 = LD(e + 6), s7 = LD(e + 7);
                uint4 v0 = *(const uint4*)(xb_in + s0 * D + chunk * 8);
                uint4 v1 = *(const uint4*)(xb_in + s1 * D + chunk * 8);
                uint4 v2 = *(const uint4*)(xb_in + s2 * D + chunk * 8);
                uint4 v3 = *(const uint4*)(xb_in + s3 * D + chunk * 8);
                uint4 v4 = *(const uint4*)(xb_in + s4 * D + chunk * 8);
                uint4 v5 = *(const uint4*)(xb_in + s5 * D + chunk * 8);
                uint4 v6 = *(const uint4*)(xb_in + s6 * D + chunk * 8);
                uint4 v7 = *(const uint4*)(xb_in + s7 * D + chunk * 8);
                ACC(v0) ACC(v1) ACC(v2) ACC(v3)
                ACC(v4) ACC(v5) ACC(v6) ACC(v7)
            }
            if (e + 3 < end) {
                int s0 = LD(e), s1 = LD(e + 1), s2 = LD(e + 2), s3 = LD(e + 3);
                uint4 v0 = *(const uint4*)(xb_in + s0 * D + chunk * 8);
                uint4 v1 = *(const uint4*)(xb_in + s1 * D + chunk * 8);
                uint4 v2 = *(const uint4*)(xb_in + s2 * D + chunk * 8);
                uint4 v3 = *(const uint4*)(xb_in + s3 * D + chunk * 8);
                ACC(v0) ACC(v1) ACC(v2) ACC(v3)
                e += 4;
            }
            if (e + 1 < end) {
                int s0 = LD(e), s1 = LD(e + 1);
                uint4 v0 = *(const uint4*)(xb_in + s0 * D + chunk * 8);
                uint4 v1 = *(const uint4*)(xb_in + s1 * D + chunk * 8);
                ACC(v0) ACC(v1)
                e += 2;
            }
            if (e < end) {
                int s0 = LD(e);
                uint4 v0 = *(const uint4*)(xb_in + s0 * D + chunk * 8);
                ACC(v0)
            }
#undef ACC
            float m = ideg[node_l];
            uint4 o;
            o.x = (unsigned)f2b(a0 * m) | ((unsigned)f2b(a1 * m) << 16);
            o.y = (unsigned)f2b(a2 * m) | ((unsigned)f2b(a3 * m) << 16);
            o.z = (unsigned)f2b(a4 * m) | ((unsigned)f2b(a5 * m) << 16);
            o.w = (unsigned)f2b(a6 * m) | ((unsigned)f2b(a7 * m) << 16);
            *(uint4*)&sA[node_l * LPITCH + chunk * 8] = o;
        }
    };
    if (fits) run_gather([&](int e) { return lcol[e - e0]; });
    else      run_gather([&](int e) { return col[e]; });
    __syncthreads();

    // GEMM stage
    int q = lane >> 4;
    int ln = lane & 15;
    f32x4 acc[4] = {{0, 0, 0, 0}, {0, 0, 0, 0}, {0, 0, 0, 0}, {0, 0, 0, 0}};
    f32x4 accr[4] = {{0, 0, 0, 0}, {0, 0, 0, 0}, {0, 0, 0, 0}, {0, 0, 0, 0}};
    const u16* aRow = &sA[(w * 16 + ln) * LPITCH];

#pragma unroll
    for (int c = 0; c < 4; c++) {       // K = 128
        bf16x8 a = ld_frag(&aRow[c * 32 + q * 8]);
#pragma unroll
        for (int t = 0; t < 4; t++) {
            bf16x8 b = ld_frag(&sB[(t * 16 + ln) * LPITCH + c * 32 + q * 8]);
            acc[t] = __builtin_amdgcn_mfma_f32_16x16x32_bf16(a, b, acc[t], 0, 0, 0);
        }
    }
    if (layer0) {                       // residual = x @ w_res (one-shot global loads)
#pragma unroll
        for (int c = 0; c < 2; c++) {
            bf16x8 a = ld_frag(&aRow[64 + c * 32 + q * 8]);
#pragma unroll
            for (int t = 0; t < 4; t++) {
                bf16x8 b = ld_frag(WresT + (t * 16 + ln) * 64 + c * 32 + q * 8);
                accr[t] = __builtin_amdgcn_mfma_f32_16x16x32_bf16(a, b, accr[t], 0, 0, 0);
            }
        }
    }

    float bcol[4], gcol[4], btcol[4], brcol[4];
#pragma unroll
    for (int t = 0; t < 4; t++) {
        int colI = t * 16 + ln;
        bcol[t] = bl[colI];
        gcol[t] = gam[colI];
        btcol[t] = bet[colI];
        brcol[t] = layer0 ? bres[colI] : 0.f;
    }
#pragma unroll
    for (int t = 0; t < 4; t++)
#pragma unroll
        for (int r = 0; r < 4; r++) acc[t][r] += bcol[t];

    float ps[4], pq[4];
#pragma unroll
    for (int r = 0; r < 4; r++) {
        float s = 0, s2 = 0;
#pragma unroll
        for (int t = 0; t < 4; t++) { float h = acc[t][r]; s += h; s2 += h * h; }
        ps[r] = s; pq[r] = s2;
    }
    for (int off = 1; off < 16; off <<= 1) {
#pragma unroll
        for (int r = 0; r < 4; r++) {
            ps[r] += __shfl_xor(ps[r], off, 64);
            pq[r] += __shfl_xor(pq[r], off, 64);
        }
    }
    // epilogue -> sA cols 0..63 (wave-local rows; in-wave LDS dep, no barrier)
#pragma unroll
    for (int r = 0; r < 4; r++) {
        int nb = w * 16 + q * 4 + r;
        float mu = ps[r] * (1.f / 64.f);
        float var = pq[r] * (1.f / 64.f) - mu * mu;
        var = var < 0.f ? 0.f : var;
        float rstd = rsqrtf(var + 1e-5f);
#pragma unroll
        for (int t = 0; t < 4; t++) {
            int colI = t * 16 + ln;
            float hn = (acc[t][r] - mu) * rstd * gcol[t] + btcol[t];
            hn = hn > 0.f ? hn : 0.f;
            float res = layer0 ? (accr[t][r] + brcol[t])
                               : b2f(sA[nb * LPITCH + 64 + colI]);
            sA[nb * LPITCH + colI] = f2b(hn + res);
        }
    }

    if (final_) {
        // FC: out = x3 @ w_fc + b_fc; stage f32 through sB (dead after GEMM) for
        // coalesced float4 writeback. Pitch 68 floats breaks bank aliasing.
        f32x4 accf[4] = {{0, 0, 0, 0}, {0, 0, 0, 0}, {0, 0, 0, 0}, {0, 0, 0, 0}};
#pragma unroll
        for (int c = 0; c < 2; c++) {
            bf16x8 a = ld_frag(&aRow[c * 32 + q * 8]);
#pragma unroll
            for (int t = 0; t < 4; t++) {
                bf16x8 b = ld_frag(WfcT + (t * 16 + ln) * 64 + c * 32 + q * 8);
                accf[t] = __builtin_amdgcn_mfma_f32_16x16x32_bf16(a, b, accf[t], 0, 0, 0);
            }
        }
        __syncthreads();               // all waves done reading sB
        float* fB = (float*)sB;        // 64 rows x pitch 68 = 4352 floats = 17408 B
#pragma unroll
        for (int r = 0; r < 4; r++) {
            int nb = w * 16 + q * 4 + r;
#pragma unroll
            for (int t = 0; t < 4; t++) {
                int colI = t * 16 + ln;
                fB[nb * 68 + colI] = accf[t][r] + bfc[colI];
            }
        }
        __syncthreads();
#pragma unroll
        for (int i = 0; i < 4; i++) {
            int idx = i * 256 + tid;
            int row = idx >> 4, cc = idx & 15;
            int node = base + row;
            if (node < N)
                *(float4*)(fout + node * D + cc * 4) = *(const float4*)&fB[row * 68 + cc * 4];
        }
    } else {
        // coalesced writeback of this wave's 16 rows (2 uint4 per thread)
#pragma unroll
        for (int i = 0; i < 2; i++) {
            int idx = i * 64 + lane;
            int row = w * 16 + (idx >> 3);
            int ch = idx & 7;
            int node = base + row;
            if (node < N)
                *(uint4*)(xb_out + node * D + ch * 8) = *(const uint4*)&sA[row * LPITCH + ch * 8];
        }
    }
}

extern "C" void kernel_launch(void* const* d_in, const int* in_sizes, int n_in,
                              void* d_out, int out_size, void* d_ws, size_t ws_size,
                              hipStream_t stream) {
    const float* x_in = (const float*)d_in[0];
    const int* e_src = (const int*)d_in[1];
    const int* e_dst = (const int*)d_in[2];
    const float* w_l = (const float*)d_in[3];
    const float* b_l = (const float*)d_in[4];
    const float* w_r = (const float*)d_in[5];
    const float* gam = (const float*)d_in[6];
    const float* bet = (const float*)d_in[7];
    const float* w_res = (const float*)d_in[8];
    const float* b_res = (const float*)d_in[9];
    const float* w_fc = (const float*)d_in[10];
    const float* b_fc = (const float*)d_in[11];
    float* out = (float*)d_out;

    const int N = in_sizes[0] / D;
    const int E = in_sizes[1];
    const int nbuck = ((N - 1) >> BSHIFT) + 1;   // 196 for N=100000 (<= 512)
    const int eper = (E + CHUNKS - 1) / CHUNKS;

    size_t o = 0;
    auto carve = [&](size_t bytes) {
        size_t cur = o;
        o += (bytes + 255) & ~(size_t)255;
        return (char*)d_ws + cur;
    };
    int* row_ptr = (int*)carve((size_t)(N + 1) * 4);
    float* inv_deg = (float*)carve((size_t)N * 4);
    int* colA = (int*)carve((size_t)E * 4);
    int* staging = (int*)carve((size_t)E * 4);
    int* Hh = (int*)carve((size_t)CHUNKS * nbuck * 4);
    int* Orel = (int*)carve((size_t)CHUNKS * nbuck * 4);
    int* Tb = (int*)carve((size_t)nbuck * 4);
    int* bar = (int*)carve(2 * 4);
    u16* WtL = (u16*)carve(3 * 64 * 128 * 2);
    u16* WresT = (u16*)carve(64 * 64 * 2);
    u16* WfcT = (u16*)carve(64 * 64 * 2);
    u16* xbA = (u16*)carve((size_t)N * D * 2);
    u16* xbB = (u16*)carve((size_t)N * D * 2);

    // barrier counter must be 0 at kernel entry (generation word is don't-care)
    hipMemsetAsync(bar, 0, 8, stream);
    csr_fused<<<CHUNKS, 256, 0, stream>>>(e_src, e_dst, E,
                                          x_in, xbA, N * D / 4,
                                          w_l, w_r, w_res, w_fc, WtL, WresT, WfcT,
                                          Hh, Orel, Tb, staging,
                                          row_ptr, inv_deg, colA,
                                          bar, N, nbuck, eper);

    int gridT = (N + 63) / 64;

    // layer 0: xbA -> xbB  (residual via w_res MFMA)
    layer_kernel<<<gridT, 256, 0, stream>>>(xbA, row_ptr, colA, inv_deg, WtL,
                                            b_l, gam, bet, WresT, b_res,
                                            WfcT, b_fc, xbB, out, N, 1, 0);
    // layer 1: xbB -> xbA
    layer_kernel<<<gridT, 256, 0, stream>>>(xbB, row_ptr, colA, inv_deg, WtL + 8192,
                                            b_l + 64, gam + 64, bet + 64, WresT, b_res,
                                            WfcT, b_fc, xbA, out, N, 0, 0);
    // layer 2 + fused fc: xbA -> out (f32)
    layer_kernel<<<gridT, 256, 0, stream>>>(xbA, row_ptr, colA, inv_deg, WtL + 16384,
                                            b_l + 128, gam + 128, bet + 128, WresT, b_res,
                                            WfcT, b_fc, xbB, out, N, 0, 1);
}

// Round 5
// 275.991 us; speedup vs baseline: 7.0297x; 1.5094x over previous
//
#include <hip/hip_runtime.h>

typedef unsigned short u16;
typedef __bf16 bf16x8 __attribute__((ext_vector_type(8)));
typedef float f32x4 __attribute__((ext_vector_type(4)));

#define D 64
#define LPITCH 136   // 128 + 8 bf16 pad
#define CHUNKS 1024  // edge-array partitions (4 blocks/CU)
#define BSHIFT 9     // 512 nodes per bucket (nbuck = 196 for N = 100000; max 512)
#define CAPB 10240   // padded per-bucket staging capacity (mean 8192, +23 sigma)
#define CCAP 1280    // LDS edge-list capacity per 64-node tile (mean ~1024, +2 sigma)

__device__ __forceinline__ float b2f(u16 u) {
    unsigned v = ((unsigned)u) << 16;
    float f;
    __builtin_memcpy(&f, &v, 4);
    return f;
}
__device__ __forceinline__ float u2f_lo(unsigned u) {
    unsigned v = u << 16;
    float f;
    __builtin_memcpy(&f, &v, 4);
    return f;
}
__device__ __forceinline__ float u2f_hi(unsigned u) {
    unsigned v = u & 0xFFFF0000u;
    float f;
    __builtin_memcpy(&f, &v, 4);
    return f;
}
__device__ __forceinline__ u16 f2b(float f) {
    unsigned u;
    __builtin_memcpy(&u, &f, 4);
    u = u + 0x7FFFu + ((u >> 16) & 1u);   // RNE
    return (u16)(u >> 16);
}
__device__ __forceinline__ bf16x8 ld_frag(const u16* p) {
    union { uint4 u; bf16x8 b; } cv;
    cv.u = *(const uint4*)p;
    return cv.b;
}

// ---------------- binAB: hist -> bulk-reserve (1 atomic per block,bucket) -> scatter
// Replaces binA + binS2 + binB. Staging is PADDED: bucket b owns [b*CAPB, (b+1)*CAPB).
// Within-bucket order = arrival order (valid: segment-sum order is unspecified).
// cvt/weight tails folded in. 1024 blocks -> 4 blocks/CU.
__global__ __launch_bounds__(256) void binAB_kernel(
    const int* __restrict__ src, const int* __restrict__ dst, int E,
    int* __restrict__ gcnt,          // [nbuck], zeroed before launch
    int* __restrict__ staging,       // [nbuck*CAPB]
    const float* __restrict__ xf, u16* __restrict__ xb, int total4,
    const float* __restrict__ wl, const float* __restrict__ wr,
    const float* __restrict__ wres, const float* __restrict__ wfc,
    u16* __restrict__ WtL, u16* __restrict__ WresT, u16* __restrict__ WfcT,
    int nbuck, int eper) {
    __shared__ int hist[512];
    __shared__ int cur[512];
    int t = threadIdx.x;
    int c = blockIdx.x;
    int gid = c * 256 + t;
    int gstr = CHUNKS * 256;
    int beg = c * eper, end = min(beg + eper, E);

    hist[t] = 0;
    hist[t + 256] = 0;
    __syncthreads();
    // pass 1: chunk histogram (dst chunk ~6KB -> stays L1-hot for pass 2)
    for (int i = beg + t; i < end; i += 256)
        atomicAdd(&hist[dst[i] >> BSHIFT], 1);

    // tails (independent of hist; consumed by later dispatches)
    for (int i = gid; i < total4; i += gstr) {
        float4 v = *(const float4*)(xf + i * 4);
        ushort4 o;
        o.x = f2b(v.x); o.y = f2b(v.y); o.z = f2b(v.z); o.w = f2b(v.w);
        *(ushort4*)(xb + i * 4) = o;
    }
    for (int idx = gid; idx < 3 * 64 * 128; idx += gstr) {
        int l = idx >> 13;
        int rem = idx & 8191;
        int n = rem >> 7;
        int k = rem & 127;
        float v = (k < 64) ? wl[l * 4096 + k * 64 + n] : wr[l * 4096 + (k - 64) * 64 + n];
        WtL[idx] = f2b(v);
    }
    for (int idx = gid; idx < 4096; idx += gstr) {
        int n = idx >> 6, k = idx & 63;
        WresT[idx] = f2b(wres[k * 64 + n]);
        WfcT[idx] = f2b(wfc[k * 64 + n]);
    }
    __syncthreads();

    // bulk reservation: one global atomic per non-empty (block,bucket)
    for (int b = t; b < nbuck; b += 256) {
        int cnt = hist[b];
        int base = 0;
        if (cnt > 0) base = atomicAdd(&gcnt[b], cnt);
        cur[b] = b * CAPB + base;
    }
    __syncthreads();

    // pass 2: scatter packed (src | dlow<<17) into reserved cells
    const int mask = (1 << BSHIFT) - 1;
    int capg = CAPB;
    for (int i = beg + t; i < end; i += 256) {
        int d = dst[i];
        int b = d >> BSHIFT;
        int p = atomicAdd(&cur[b], 1);
        if (p < b * CAPB + capg)               // overflow guard (prob ~0)
            staging[p] = src[i] | ((d & mask) << 17);
    }
}

// ---------------- binC: per-bucket degree hist + scan + col scatter (LDS only) ------
// Reads padded staging bucket [b*CAPB, b*CAPB+T[b]); writes compact col/row_ptr.
__global__ __launch_bounds__(256) void binC_kernel(const int* __restrict__ staging,
                                                   const int* __restrict__ T,
                                                   int* __restrict__ row_ptr,
                                                   float* __restrict__ inv_deg,
                                                   int* __restrict__ col, int N, int nbuck) {
    __shared__ int cnt[512];
    __shared__ int lrp[512];
    __shared__ int sm[256];
    __shared__ int span[2];
    int b = blockIdx.x;
    int t = threadIdx.x;
    // compact bucket base via local scan of (clamped) T
    int v = (t < nbuck) ? min(T[t], CAPB) : 0;
    sm[t] = v;
    __syncthreads();
    for (int off = 1; off < 256; off <<= 1) {
        int u = (t >= off) ? sm[t - off] : 0;
        __syncthreads();
        sm[t] += u;
        __syncthreads();
    }
    if (t == b) { span[0] = sm[t] - v; span[1] = sm[t]; }
    if (b == 0 && t == 255) row_ptr[N] = sm[255];   // compact total (== E normally)
    cnt[t] = 0;
    cnt[t + 256] = 0;
    __syncthreads();
    int sbeg = span[0];
    int scount = span[1] - span[0];
    int pbeg = b * CAPB;
    int node0 = b << BSHIFT;
    int nn = min(1 << BSHIFT, N - node0);
    for (int i = t; i < scount; i += 256)
        atomicAdd(&cnt[staging[pbeg + i] >> 17], 1);
    __syncthreads();
    int c0 = cnt[2 * t], c1 = cnt[2 * t + 1];
    sm[t] = c0 + c1;
    __syncthreads();
    for (int off = 1; off < 256; off <<= 1) {
        int u = (t >= off) ? sm[t - off] : 0;
        __syncthreads();
        sm[t] += u;
        __syncthreads();
    }
    int excl = sm[t] - c0 - c1;
    lrp[2 * t] = excl;
    lrp[2 * t + 1] = excl + c0;
    __syncthreads();
    for (int i = t; i < nn; i += 256) {
        row_ptr[node0 + i] = sbeg + lrp[i];
        int dd = cnt[i];
        inv_deg[node0 + i] = dd > 0 ? 1.0f / (float)dd : 0.0f;
    }
    __syncthreads();
    for (int i = t; i < scount; i += 256) {
        int word = staging[pbeg + i];
        int ld = word >> 17;
        int k = atomicSub(&cnt[ld], 1) - 1;
        col[sbeg + lrp[ld] + k] = word & 0x1FFFF;
    }
}

// ---------------- fused SAGE layer: gather-mean + GEMM + LN + ReLU + residual --------
// R9 static-slot gather (best measured) + tile edge-list staged to LDS (lcol).
// NOTE (R3 lesson): LDS f32-atomic aggregation is ~13x slower (ds_add ~1/cyc/CU);
// register slot-accumulation + per-node-sorted col is the fast structure.
__global__ __launch_bounds__(256, 4) void layer_kernel(const u16* __restrict__ xb_in,
                                                       const int* __restrict__ row_ptr,
                                                       const int* __restrict__ col,
                                                       const float* __restrict__ inv_deg,
                                                       const u16* __restrict__ Wt,    // [64][128]
                                                       const float* __restrict__ bl,
                                                       const float* __restrict__ gam,
                                                       const float* __restrict__ bet,
                                                       const u16* __restrict__ WresT, // [64][64]
                                                       const float* __restrict__ bres,
                                                       const u16* __restrict__ WfcT,  // [64][64]
                                                       const float* __restrict__ bfc,
                                                       u16* __restrict__ xb_out,
                                                       float* __restrict__ fout,
                                                       int N, int layer0, int final_) {
    __shared__ __align__(16) u16 sA[64 * LPITCH];
    __shared__ __align__(16) u16 sB[64 * LPITCH];   // weights; reused as f32 stage in final
    __shared__ int lcol[CCAP];
    __shared__ int rp[65];
    __shared__ float ideg[64];
    int tid = threadIdx.x;
    int base = blockIdx.x * 64;
    int lane = tid & 63;
    int w = tid >> 6;

    // stage B (W^T rows), 4 uint4 per thread
#pragma unroll
    for (int i = 0; i < 4; i++) {
        int idx = i * 256 + tid;
        int r = idx >> 4, c = idx & 15;
        *(uint4*)&sB[r * LPITCH + c * 8] = *(const uint4*)(Wt + idx * 8);
    }
    // stage x rows into sA cols 64..127, 2 uint4 per thread
#pragma unroll
    for (int i = 0; i < 2; i++) {
        int idx = i * 256 + tid;
        int r = idx >> 3, c = idx & 7;
        int node = base + r;
        uint4 v = make_uint4(0, 0, 0, 0);
        if (node < N) v = *(const uint4*)(xb_in + node * D + c * 8);
        *(uint4*)&sA[r * LPITCH + 64 + c * 8] = v;
    }
    if (tid < 65) rp[tid] = row_ptr[min(base + tid, N)];
    if (tid < 64) ideg[tid] = (base + tid < N) ? inv_deg[base + tid] : 0.f;
    __syncthreads();

    int e0 = rp[0];
    int tileE = rp[64] - e0;
    bool fits = tileE <= CCAP;
    if (fits) {
        for (int i = tid; i < tileE; i += 256) lcol[i] = col[e0 + i];
    }
    __syncthreads();

    // gather stage: slot-per-node, 2 rounds x 8 slots per wave = 16 nodes/wave
    int slot = lane >> 3;
    int chunk = lane & 7;
    auto run_gather = [&](auto LD) {
#pragma unroll
        for (int r = 0; r < 2; r++) {
            int node_l = w * 16 + r * 8 + slot;
            float a0 = 0, a1 = 0, a2 = 0, a3 = 0, a4 = 0, a5 = 0, a6 = 0, a7 = 0;
            int e = rp[node_l], end = rp[node_l + 1];
#define ACC(v)                                          \
    a0 += u2f_lo(v.x); a1 += u2f_hi(v.x);               \
    a2 += u2f_lo(v.y); a3 += u2f_hi(v.y);               \
    a4 += u2f_lo(v.z); a5 += u2f_hi(v.z);               \
    a6 += u2f_lo(v.w); a7 += u2f_hi(v.w);
            for (; e + 7 < end; e += 8) {
                int s0 = LD(e),     s1 = LD(e + 1), s2 = LD(e + 2), s3 = LD(e + 3);
                int s4 = LD(e + 4), s5 = LD(e + 5), s6 = LD(e + 6), s7 = LD(e + 7);
                uint4 v0 = *(const uint4*)(xb_in + s0 * D + chunk * 8);
                uint4 v1 = *(const uint4*)(xb_in + s1 * D + chunk * 8);
                uint4 v2 = *(const uint4*)(xb_in + s2 * D + chunk * 8);
                uint4 v3 = *(const uint4*)(xb_in + s3 * D + chunk * 8);
                uint4 v4 = *(const uint4*)(xb_in + s4 * D + chunk * 8);
                uint4 v5 = *(const uint4*)(xb_in + s5 * D + chunk * 8);
                uint4 v6 = *(const uint4*)(xb_in + s6 * D + chunk * 8);
                uint4 v7 = *(const uint4*)(xb_in + s7 * D + chunk * 8);
                ACC(v0) ACC(v1) ACC(v2) ACC(v3)
                ACC(v4) ACC(v5) ACC(v6) ACC(v7)
            }
            if (e + 3 < end) {
                int s0 = LD(e), s1 = LD(e + 1), s2 = LD(e + 2), s3 = LD(e + 3);
                uint4 v0 = *(const uint4*)(xb_in + s0 * D + chunk * 8);
                uint4 v1 = *(const uint4*)(xb_in + s1 * D + chunk * 8);
                uint4 v2 = *(const uint4*)(xb_in + s2 * D + chunk * 8);
                uint4 v3 = *(const uint4*)(xb_in + s3 * D + chunk * 8);
                ACC(v0) ACC(v1) ACC(v2) ACC(v3)
                e += 4;
            }
            if (e + 1 < end) {
                int s0 = LD(e), s1 = LD(e + 1);
                uint4 v0 = *(const uint4*)(xb_in + s0 * D + chunk * 8);
                uint4 v1 = *(const uint4*)(xb_in + s1 * D + chunk * 8);
                ACC(v0) ACC(v1)
                e += 2;
            }
            if (e < end) {
                int s0 = LD(e);
                uint4 v0 = *(const uint4*)(xb_in + s0 * D + chunk * 8);
                ACC(v0)
            }
#undef ACC
            float m = ideg[node_l];
            uint4 o;
            o.x = (unsigned)f2b(a0 * m) | ((unsigned)f2b(a1 * m) << 16);
            o.y = (unsigned)f2b(a2 * m) | ((unsigned)f2b(a3 * m) << 16);
            o.z = (unsigned)f2b(a4 * m) | ((unsigned)f2b(a5 * m) << 16);
            o.w = (unsigned)f2b(a6 * m) | ((unsigned)f2b(a7 * m) << 16);
            *(uint4*)&sA[node_l * LPITCH + chunk * 8] = o;
        }
    };
    if (fits) run_gather([&](int e) { return lcol[e - e0]; });
    else      run_gather([&](int e) { return col[e]; });
    __syncthreads();

    // GEMM stage
    int q = lane >> 4;
    int ln = lane & 15;
    f32x4 acc[4] = {{0, 0, 0, 0}, {0, 0, 0, 0}, {0, 0, 0, 0}, {0, 0, 0, 0}};
    f32x4 accr[4] = {{0, 0, 0, 0}, {0, 0, 0, 0}, {0, 0, 0, 0}, {0, 0, 0, 0}};
    const u16* aRow = &sA[(w * 16 + ln) * LPITCH];

#pragma unroll
    for (int c = 0; c < 4; c++) {       // K = 128
        bf16x8 a = ld_frag(&aRow[c * 32 + q * 8]);
#pragma unroll
        for (int t = 0; t < 4; t++) {
            bf16x8 b = ld_frag(&sB[(t * 16 + ln) * LPITCH + c * 32 + q * 8]);
            acc[t] = __builtin_amdgcn_mfma_f32_16x16x32_bf16(a, b, acc[t], 0, 0, 0);
        }
    }
    if (layer0) {                       // residual = x @ w_res (one-shot global loads)
#pragma unroll
        for (int c = 0; c < 2; c++) {
            bf16x8 a = ld_frag(&aRow[64 + c * 32 + q * 8]);
#pragma unroll
            for (int t = 0; t < 4; t++) {
                bf16x8 b = ld_frag(WresT + (t * 16 + ln) * 64 + c * 32 + q * 8);
                accr[t] = __builtin_amdgcn_mfma_f32_16x16x32_bf16(a, b, accr[t], 0, 0, 0);
            }
        }
    }

    float bcol[4], gcol[4], btcol[4], brcol[4];
#pragma unroll
    for (int t = 0; t < 4; t++) {
        int colI = t * 16 + ln;
        bcol[t] = bl[colI];
        gcol[t] = gam[colI];
        btcol[t] = bet[colI];
        brcol[t] = layer0 ? bres[colI] : 0.f;
    }
#pragma unroll
    for (int t = 0; t < 4; t++)
#pragma unroll
        for (int r = 0; r < 4; r++) acc[t][r] += bcol[t];

    float ps[4], pq[4];
#pragma unroll
    for (int r = 0; r < 4; r++) {
        float s = 0, s2 = 0;
#pragma unroll
        for (int t = 0; t < 4; t++) { float h = acc[t][r]; s += h; s2 += h * h; }
        ps[r] = s; pq[r] = s2;
    }
    for (int off = 1; off < 16; off <<= 1) {
#pragma unroll
        for (int r = 0; r < 4; r++) {
            ps[r] += __shfl_xor(ps[r], off, 64);
            pq[r] += __shfl_xor(pq[r], off, 64);
        }
    }
    // epilogue -> sA cols 0..63 (wave-local rows; in-wave LDS dep, no barrier)
#pragma unroll
    for (int r = 0; r < 4; r++) {
        int nb = w * 16 + q * 4 + r;
        float mu = ps[r] * (1.f / 64.f);
        float var = pq[r] * (1.f / 64.f) - mu * mu;
        var = var < 0.f ? 0.f : var;
        float rstd = rsqrtf(var + 1e-5f);
#pragma unroll
        for (int t = 0; t < 4; t++) {
            int colI = t * 16 + ln;
            float hn = (acc[t][r] - mu) * rstd * gcol[t] + btcol[t];
            hn = hn > 0.f ? hn : 0.f;
            float res = layer0 ? (accr[t][r] + brcol[t])
                               : b2f(sA[nb * LPITCH + 64 + colI]);
            sA[nb * LPITCH + colI] = f2b(hn + res);
        }
    }

    if (final_) {
        // FC: out = x3 @ w_fc + b_fc; stage f32 through sB (dead after GEMM) for
        // coalesced float4 writeback. Pitch 68 floats breaks bank aliasing.
        f32x4 accf[4] = {{0, 0, 0, 0}, {0, 0, 0, 0}, {0, 0, 0, 0}, {0, 0, 0, 0}};
#pragma unroll
        for (int c = 0; c < 2; c++) {
            bf16x8 a = ld_frag(&aRow[c * 32 + q * 8]);
#pragma unroll
            for (int t = 0; t < 4; t++) {
                bf16x8 b = ld_frag(WfcT + (t * 16 + ln) * 64 + c * 32 + q * 8);
                accf[t] = __builtin_amdgcn_mfma_f32_16x16x32_bf16(a, b, accf[t], 0, 0, 0);
            }
        }
        __syncthreads();               // all waves done reading sB
        float* fB = (float*)sB;        // 64 rows x pitch 68 = 4352 floats = 17408 B
#pragma unroll
        for (int r = 0; r < 4; r++) {
            int nb = w * 16 + q * 4 + r;
#pragma unroll
            for (int t = 0; t < 4; t++) {
                int colI = t * 16 + ln;
                fB[nb * 68 + colI] = accf[t][r] + bfc[colI];
            }
        }
        __syncthreads();
#pragma unroll
        for (int i = 0; i < 4; i++) {
            int idx = i * 256 + tid;
            int row = idx >> 4, cc = idx & 15;
            int node = base + row;
            if (node < N)
                *(float4*)(fout + node * D + cc * 4) = *(const float4*)&fB[row * 68 + cc * 4];
        }
    } else {
        // coalesced writeback of this wave's 16 rows (2 uint4 per thread)
#pragma unroll
        for (int i = 0; i < 2; i++) {
            int idx = i * 64 + lane;
            int row = w * 16 + (idx >> 3);
            int ch = idx & 7;
            int node = base + row;
            if (node < N)
                *(uint4*)(xb_out + node * D + ch * 8) = *(const uint4*)&sA[row * LPITCH + ch * 8];
        }
    }
}

extern "C" void kernel_launch(void* const* d_in, const int* in_sizes, int n_in,
                              void* d_out, int out_size, void* d_ws, size_t ws_size,
                              hipStream_t stream) {
    const float* x_in = (const float*)d_in[0];
    const int* e_src = (const int*)d_in[1];
    const int* e_dst = (const int*)d_in[2];
    const float* w_l = (const float*)d_in[3];
    const float* b_l = (const float*)d_in[4];
    const float* w_r = (const float*)d_in[5];
    const float* gam = (const float*)d_in[6];
    const float* bet = (const float*)d_in[7];
    const float* w_res = (const float*)d_in[8];
    const float* b_res = (const float*)d_in[9];
    const float* w_fc = (const float*)d_in[10];
    const float* b_fc = (const float*)d_in[11];
    float* out = (float*)d_out;

    const int N = in_sizes[0] / D;
    const int E = in_sizes[1];
    const int nbuck = ((N - 1) >> BSHIFT) + 1;   // 196 for N=100000 (<= 512)
    const int eper = (E + CHUNKS - 1) / CHUNKS;

    size_t o = 0;
    auto carve = [&](size_t bytes) {
        size_t cur = o;
        o += (bytes + 255) & ~(size_t)255;
        return (char*)d_ws + cur;
    };
    int* row_ptr = (int*)carve((size_t)(N + 1) * 4);
    float* inv_deg = (float*)carve((size_t)N * 4);
    int* colA = (int*)carve((size_t)E * 4);
    int* staging = (int*)carve((size_t)nbuck * CAPB * 4);
    int* gcnt = (int*)carve((size_t)nbuck * 4);
    u16* WtL = (u16*)carve(3 * 64 * 128 * 2);
    u16* WresT = (u16*)carve(64 * 64 * 2);
    u16* WfcT = (u16*)carve(64 * 64 * 2);
    u16* xbA = (u16*)carve((size_t)N * D * 2);
    u16* xbB = (u16*)carve((size_t)N * D * 2);

    // CSR build: binAB (hist + bulk-reserve + scatter, tails folded) -> binC (sort)
    hipMemsetAsync(gcnt, 0, (size_t)nbuck * 4, stream);
    binAB_kernel<<<CHUNKS, 256, 0, stream>>>(e_src, e_dst, E, gcnt, staging,
                                             x_in, xbA, N * D / 4,
                                             w_l, w_r, w_res, w_fc, WtL, WresT, WfcT,
                                             nbuck, eper);
    binC_kernel<<<nbuck, 256, 0, stream>>>(staging, gcnt, row_ptr, inv_deg, colA,
                                           N, nbuck);

    int gridT = (N + 63) / 64;

    // layer 0: xbA -> xbB  (residual via w_res MFMA)
    layer_kernel<<<gridT, 256, 0, stream>>>(xbA, row_ptr, colA, inv_deg, WtL,
                                            b_l, gam, bet, WresT, b_res,
                                            WfcT, b_fc, xbB, out, N, 1, 0);
    // layer 1: xbB -> xbA
    layer_kernel<<<gridT, 256, 0, stream>>>(xbB, row_ptr, colA, inv_deg, WtL + 8192,
                                            b_l + 64, gam + 64, bet + 64, WresT, b_res,
                                            WfcT, b_fc, xbA, out, N, 0, 0);
    // layer 2 + fused fc: xbA -> out (f32)
    layer_kernel<<<gridT, 256, 0, stream>>>(xbA, row_ptr, colA, inv_deg, WtL + 16384,
                                            b_l + 128, gam + 128, bet + 128, WresT, b_res,
                                            WfcT, b_fc, xbB, out, N, 0, 1);
}